// Round 4
// baseline (350.390 us; speedup 1.0000x reference)
//
#include <hip/hip_runtime.h>
#include <hip/hip_bf16.h>
#include <cstdint>
#include <cstddef>

typedef __attribute__((ext_vector_type(8))) short short8;
typedef __attribute__((ext_vector_type(4))) float f32x4;
typedef __attribute__((ext_vector_type(4))) uint16_t ushort4_t;

__device__ __forceinline__ uint16_t f2bf(float f) {
  union { float f; uint32_t u; } v; v.f = f;
  uint32_t r = v.u + 0x7FFFu + ((v.u >> 16) & 1u);
  return (uint16_t)(r >> 16);
}

__device__ __forceinline__ uint16_t f2bf_hw(float f) {
  union { __hip_bfloat16 h; uint16_t u; } cv;
  cv.h = __float2bfloat16(f);
  return cv.u;
}

// ---------------- conversion kernels ----------------

__global__ __launch_bounds__(256) void cvt_f32_bf16(const float* __restrict__ in,
                                                    uint16_t* __restrict__ out, int n4) {
  int i = blockIdx.x * 256 + threadIdx.x;
  int stride = gridDim.x * 256;
  for (; i < n4; i += stride) {
    float4 v = ((const float4*)in)[i];
    ushort4_t o = { f2bf(v.x), f2bf(v.y), f2bf(v.z), f2bf(v.w) };
    ((ushort4_t*)out)[i] = o;
  }
}

// out[C][R] (bf16) = transpose of in[R][C] (f32)
__global__ __launch_bounds__(256) void transpose_cvt(const float* __restrict__ in,
                                                     uint16_t* __restrict__ out, int R, int C) {
  __shared__ float tile[32][33];
  int c0 = blockIdx.x * 32, r0 = blockIdx.y * 32;
  int tx = threadIdx.x, ty = threadIdx.y;
#pragma unroll
  for (int j = 0; j < 32; j += 8)
    tile[ty + j][tx] = in[(size_t)(r0 + ty + j) * C + c0 + tx];
  __syncthreads();
#pragma unroll
  for (int j = 0; j < 32; j += 8)
    out[(size_t)(c0 + ty + j) * R + r0 + tx] = f2bf(tile[tx][ty + j]);
}

// v [BH][2048][64] bf16 -> vT [BH][64][2048] bf16
__global__ __launch_bounds__(256) void transpose_v(const uint16_t* __restrict__ in,
                                                   uint16_t* __restrict__ out) {
  __shared__ uint16_t tile[32][33];
  int bh = blockIdx.z;
  int t0 = blockIdx.x * 32, d0 = blockIdx.y * 32;
  const uint16_t* ip = in + (size_t)bh * 2048 * 64;
  uint16_t* op = out + (size_t)bh * 64 * 2048;
  int tx = threadIdx.x, ty = threadIdx.y;
#pragma unroll
  for (int j = 0; j < 32; j += 8)
    tile[ty + j][tx] = ip[(size_t)(t0 + ty + j) * 64 + d0 + tx];
  __syncthreads();
#pragma unroll
  for (int j = 0; j < 32; j += 8)
    op[(size_t)(d0 + ty + j) * 2048 + t0 + tx] = tile[tx][ty + j];
}

// ---------------- GEMM (128x128 tile, BK=64, 4 waves) ----------------

__device__ __forceinline__ void stage16(const uint16_t* g, uint16_t* lds) {
  __builtin_amdgcn_global_load_lds((__attribute__((address_space(1))) void*)g,
                                   (__attribute__((address_space(3))) void*)lds, 16, 0, 0);
}

// C[M][N] = A[M][K] * Bt[N][K]^T + bias
// MODE 0: scatter bf16 into q/k/v [B,H,T,D]; MODE 1: plain f32 row-major out
template <int MODE>
__global__ __launch_bounds__(256) void gemm128(
    const uint16_t* __restrict__ A, const uint16_t* __restrict__ Bt,
    const float* __restrict__ bias, int K,
    uint16_t* __restrict__ q_out, uint16_t* __restrict__ k_out, uint16_t* __restrict__ v_out,
    float* __restrict__ f_out, int N) {
  __shared__ uint16_t lA[128 * 64];
  __shared__ uint16_t lB[128 * 64];
  const int tid = threadIdx.x;
  const int lane = tid & 63;
  const int w = tid >> 6, wm = w >> 1, wn = w & 1;
  const int r16 = lane & 15, hi = lane >> 4;
  const int bn = blockIdx.x, bm = blockIdx.y;

  f32x4 acc[4][4];
#pragma unroll
  for (int i = 0; i < 4; ++i)
#pragma unroll
    for (int j = 0; j < 4; ++j) acc[i][j] = (f32x4){0.f, 0.f, 0.f, 0.f};

  const int ksteps = K >> 6;
  for (int kt = 0; kt < ksteps; ++kt) {
#pragma unroll
    for (int it = 0; it < 4; ++it) {
      int ci = it * 256 + tid;       // 16B chunk index, 0..1023
      int row = ci >> 3;             // tile row 0..127
      int cch = (ci & 7) ^ (row & 7);// swizzled source column-chunk
      stage16(A + (size_t)(bm * 128 + row) * K + kt * 64 + cch * 8, &lA[ci * 8]);
      stage16(Bt + (size_t)(bn * 128 + row) * K + kt * 64 + cch * 8, &lB[ci * 8]);
    }
    __syncthreads();
#pragma unroll
    for (int kk = 0; kk < 2; ++kk) {
      short8 af[4], bfr[4];
      int swz = (kk * 64 + hi * 16) ^ ((r16 & 7) << 4);  // byte offset within 128B row
#pragma unroll
      for (int i = 0; i < 4; ++i) {
        int rowa = wm * 64 + i * 16 + r16;
        af[i] = *(const short8*)((const char*)lA + rowa * 128 + swz);
        int rowb = wn * 64 + i * 16 + r16;
        bfr[i] = *(const short8*)((const char*)lB + rowb * 128 + swz);
      }
#pragma unroll
      for (int i = 0; i < 4; ++i)
#pragma unroll
        for (int j = 0; j < 4; ++j)
          acc[i][j] = __builtin_amdgcn_mfma_f32_16x16x32_bf16(af[i], bfr[j], acc[i][j], 0, 0, 0);
    }
    __syncthreads();
  }

  // epilogue: D row = (lane>>4)*4 + r, col = lane&15  [verified m89/m91]
#pragma unroll
  for (int i = 0; i < 4; ++i) {
    int rbase = bm * 128 + wm * 64 + i * 16 + hi * 4;
#pragma unroll
    for (int j = 0; j < 4; ++j) {
      int cg = bn * 128 + wn * 64 + j * 16 + r16;
      float bv = bias[cg];
      if (MODE == 0) {
        int which = cg >> 10, hh = (cg >> 6) & 15, dd = cg & 63;
        uint16_t* dst = which == 0 ? q_out : (which == 1 ? k_out : v_out);
#pragma unroll
        for (int r = 0; r < 4; ++r) {
          int rg = rbase + r;
          int bb = rg >> 11, tt = rg & 2047;
          dst[((size_t)(bb * 16 + hh) * 2048 + tt) * 64 + dd] = f2bf(acc[i][j][r] + bv);
        }
      } else {
#pragma unroll
        for (int r = 0; r < 4; ++r) {
          int rg = rbase + r;
          f_out[(size_t)rg * N + cg] = acc[i][j][r] + bv;
        }
      }
    }
  }
}

// ---------------- causal flash attention ----------------
// Q,K: [BH][2048][64] bf16; Vt: [BH][64][2048] bf16; O: [B,T,C] bf16
// Block = 2 waves sharing a balanced strip-pair (s, 63-s), processed
// sequentially; per strip the KV tiles are split between the two waves
// (split-KV). Fixed-max softmax makes the merge a plain sum (o, l) via LDS.
// Every block does exactly ~33 tiles -> 8 blocks/CU, all resident, flat
// occupancy. bid decode pins each bh's K/V to one XCD's L2.
__global__ __launch_bounds__(128, 4) void attn_fwd(
    const uint16_t* __restrict__ Qm, const uint16_t* __restrict__ Km,
    const uint16_t* __restrict__ Vt, uint16_t* __restrict__ O) {
  __shared__ uint16_t plds[2][16 * 72];  // per-wave P staging (rows padded to 72)
  __shared__ float mrg[34][64];          // wave1 partials: 32 o + 2 l per lane
  const int lane = threadIdx.x & 63;
  const int w = threadIdx.x >> 6;
  const int r16 = lane & 15, hi = lane >> 4;
  const int bid = blockIdx.x;
  const int pair = (bid >> 3) & 31;
  const int bh = (bid & 7) + ((bid >> 8) << 3);
  const int b = bh >> 4, h = bh & 15;
  const size_t base = (size_t)bh * 2048 * 64;

  const float SC = 0.18033688011112042f;   // 0.125 * log2(e)
  const float BIAS = -20.197730572445487f; // -14 * log2(e)

  short8 ones8;
#pragma unroll
  for (int i = 0; i < 8; ++i) ones8[i] = (short)0x3F80;  // bf16 1.0

  for (int halfp = 0; halfp < 2; ++halfp) {
    const int ss = halfp ? (63 - pair) : pair;
    const int q0 = ss * 32;
    const int nt = (ss >> 1) + 1;
    const int tsplit = (nt + 1) >> 1;
    const int t0 = w ? tsplit : 0;
    const int t1 = w ? nt : tsplit;

    short8 aq[2][2];
#pragma unroll
    for (int st = 0; st < 2; ++st)
#pragma unroll
      for (int c = 0; c < 2; ++c)
        aq[st][c] = *(const short8*)&Qm[base + (size_t)(q0 + st * 16 + r16) * 64 + c * 32 + hi * 8];

    f32x4 o[2][4];   // O^T fragments: col=q (r16), row=d (j*16+hi*4+r)
    f32x4 o4[2];     // l accumulator (every reg = l[q=r16])
#pragma unroll
    for (int st = 0; st < 2; ++st) {
#pragma unroll
      for (int j = 0; j < 4; ++j) o[st][j] = (f32x4){0.f, 0.f, 0.f, 0.f};
      o4[st] = (f32x4){0.f, 0.f, 0.f, 0.f};
    }

    for (int t = t0; t < t1; ++t) {
      const int kv0 = t << 6;
      const bool maskt = (t == nt - 1);
      short8 bk[4][2];
#pragma unroll
      for (int ct = 0; ct < 4; ++ct)
#pragma unroll
        for (int c = 0; c < 2; ++c)
          bk[ct][c] = *(const short8*)&Km[base + (size_t)(kv0 + ct * 16 + r16) * 64 + c * 32 + hi * 8];

#pragma unroll
      for (int st = 0; st < 2; ++st) {
        f32x4 sc[4];
#pragma unroll
        for (int ct = 0; ct < 4; ++ct) sc[ct] = (f32x4){0.f, 0.f, 0.f, 0.f};
#pragma unroll
        for (int ct = 0; ct < 4; ++ct)
#pragma unroll
          for (int c = 0; c < 2; ++c)
            sc[ct] = __builtin_amdgcn_mfma_f32_16x16x32_bf16(aq[st][c], bk[ct][c], sc[ct], 0, 0, 0);

        uint16_t* pl = &plds[w][0];
        const int rowq = q0 + st * 16 + hi * 4;
#pragma unroll
        for (int ct = 0; ct < 4; ++ct)
#pragma unroll
          for (int r = 0; r < 4; ++r) {
            float p = exp2f(fmaf(sc[ct][r], SC, BIAS));
            if (maskt && (kv0 + ct * 16 + r16) > (rowq + r)) p = 0.f;
            pl[(hi * 4 + r) * 72 + ct * 16 + r16] = f2bf_hw(p);
          }

        // order LDS writes before reads (single wave, DS pipe in-order)
        asm volatile("s_waitcnt lgkmcnt(0)" ::: "memory");
        __builtin_amdgcn_sched_barrier(0);

        short8 ap[2];
#pragma unroll
        for (int ks = 0; ks < 2; ++ks)
          ap[ks] = *(const short8*)&plds[w][r16 * 72 + ks * 32 + hi * 8];
#pragma unroll
        for (int ks = 0; ks < 2; ++ks)
          o4[st] = __builtin_amdgcn_mfma_f32_16x16x32_bf16(ones8, ap[ks], o4[st], 0, 0, 0);
#pragma unroll
        for (int ks = 0; ks < 2; ++ks) {
          short8 bv[4];
#pragma unroll
          for (int j = 0; j < 4; ++j)
            bv[j] = *(const short8*)&Vt[base + (size_t)(j * 16 + r16) * 2048 + kv0 + ks * 32 + hi * 8];
#pragma unroll
          for (int j = 0; j < 4; ++j)
            o[st][j] = __builtin_amdgcn_mfma_f32_16x16x32_bf16(bv[j], ap[ks], o[st][j], 0, 0, 0);
        }
      }
    }

    __syncthreads();
    if (w == 1) {
#pragma unroll
      for (int st = 0; st < 2; ++st) {
#pragma unroll
        for (int j = 0; j < 4; ++j)
#pragma unroll
          for (int r = 0; r < 4; ++r)
            mrg[st * 16 + j * 4 + r][lane] = o[st][j][r];
        mrg[32 + st][lane] = o4[st][0];
      }
    }
    __syncthreads();
    if (w == 0) {
#pragma unroll
      for (int st = 0; st < 2; ++st) {
        float lsum = o4[st][0] + mrg[32 + st][lane];
        float inv = 1.f / lsum;
        int qg = q0 + st * 16 + r16;
        size_t rowo = ((size_t)(b * 2048 + qg)) * 1024 + h * 64;
#pragma unroll
        for (int j = 0; j < 4; ++j) {
          float v0 = o[st][j][0] + mrg[st * 16 + j * 4 + 0][lane];
          float v1 = o[st][j][1] + mrg[st * 16 + j * 4 + 1][lane];
          float v2 = o[st][j][2] + mrg[st * 16 + j * 4 + 2][lane];
          float v3 = o[st][j][3] + mrg[st * 16 + j * 4 + 3][lane];
          ushort4_t v4 = { f2bf(v0 * inv), f2bf(v1 * inv), f2bf(v2 * inv), f2bf(v3 * inv) };
          *(ushort4_t*)&O[rowo + j * 16 + hi * 4] = v4;
        }
      }
    }
  }
}

// ---------------- launch ----------------

extern "C" void kernel_launch(void* const* d_in, const int* in_sizes, int n_in,
                              void* d_out, int out_size, void* d_ws, size_t ws_size,
                              hipStream_t stream) {
  const float* x = (const float*)d_in[0];
  const float* w_qkv = (const float*)d_in[1];
  const float* b_qkv = (const float*)d_in[2];
  const float* w_out = (const float*)d_in[3];
  const float* b_out = (const float*)d_in[4];
  float* out = (float*)d_out;

  const size_t BT = 8192, C = 1024, N3 = 3072, BHTD = 8388608;
  char* p = (char*)d_ws;
  uint16_t* xbf = (uint16_t*)p;   p += BT * C * 2;
  uint16_t* wqkvT = (uint16_t*)p; p += N3 * C * 2;
  uint16_t* woutT = (uint16_t*)p; p += C * C * 2;
  uint16_t* qb = (uint16_t*)p;    p += BHTD * 2;
  uint16_t* kb = (uint16_t*)p;    p += BHTD * 2;
  uint16_t* vb = (uint16_t*)p;    p += BHTD * 2;
  uint16_t* vtb = (uint16_t*)p;   p += BHTD * 2;
  uint16_t* ob = (uint16_t*)p;    p += BHTD * 2;

  cvt_f32_bf16<<<2048, 256, 0, stream>>>(x, xbf, (int)(BT * C / 4));
  transpose_cvt<<<dim3(96, 32), dim3(32, 8), 0, stream>>>(w_qkv, wqkvT, 1024, 3072);
  transpose_cvt<<<dim3(32, 32), dim3(32, 8), 0, stream>>>(w_out, woutT, 1024, 1024);
  gemm128<0><<<dim3(24, 64), 256, 0, stream>>>(xbf, wqkvT, b_qkv, 1024, qb, kb, vb, nullptr, 3072);
  transpose_v<<<dim3(64, 2, 64), dim3(32, 8), 0, stream>>>(vb, vtb);
  attn_fwd<<<2048, 128, 0, stream>>>(qb, kb, vtb, ob);
  gemm128<1><<<dim3(8, 64), 256, 0, stream>>>(ob, woutT, b_out, 1024, nullptr, nullptr, nullptr, out, 1024);
}

// Round 5
// 325.223 us; speedup vs baseline: 1.0774x; 1.0774x over previous
//
#include <hip/hip_runtime.h>
#include <hip/hip_bf16.h>
#include <cstdint>
#include <cstddef>

typedef __attribute__((ext_vector_type(8))) short short8;
typedef __attribute__((ext_vector_type(4))) float f32x4;
typedef __attribute__((ext_vector_type(4))) uint16_t ushort4_t;

__device__ __forceinline__ uint16_t f2bf(float f) {
  union { float f; uint32_t u; } v; v.f = f;
  uint32_t r = v.u + 0x7FFFu + ((v.u >> 16) & 1u);
  return (uint16_t)(r >> 16);
}

__device__ __forceinline__ uint16_t f2bf_hw(float f) {
  union { __hip_bfloat16 h; uint16_t u; } cv;
  cv.h = __float2bfloat16(f);
  return cv.u;
}

// ---------------- conversion kernels ----------------

__global__ __launch_bounds__(256) void cvt_f32_bf16(const float* __restrict__ in,
                                                    uint16_t* __restrict__ out, int n4) {
  int i = blockIdx.x * 256 + threadIdx.x;
  int stride = gridDim.x * 256;
  for (; i < n4; i += stride) {
    float4 v = ((const float4*)in)[i];
    ushort4_t o = { f2bf(v.x), f2bf(v.y), f2bf(v.z), f2bf(v.w) };
    ((ushort4_t*)out)[i] = o;
  }
}

// out[C][R] (bf16) = transpose of in[R][C] (f32)
__global__ __launch_bounds__(256) void transpose_cvt(const float* __restrict__ in,
                                                     uint16_t* __restrict__ out, int R, int C) {
  __shared__ float tile[32][33];
  int c0 = blockIdx.x * 32, r0 = blockIdx.y * 32;
  int tx = threadIdx.x, ty = threadIdx.y;
#pragma unroll
  for (int j = 0; j < 32; j += 8)
    tile[ty + j][tx] = in[(size_t)(r0 + ty + j) * C + c0 + tx];
  __syncthreads();
#pragma unroll
  for (int j = 0; j < 32; j += 8)
    out[(size_t)(c0 + ty + j) * R + r0 + tx] = f2bf(tile[tx][ty + j]);
}

// v [BH][2048][64] bf16 -> vT [BH][64][2048] bf16
__global__ __launch_bounds__(256) void transpose_v(const uint16_t* __restrict__ in,
                                                   uint16_t* __restrict__ out) {
  __shared__ uint16_t tile[32][33];
  int bh = blockIdx.z;
  int t0 = blockIdx.x * 32, d0 = blockIdx.y * 32;
  const uint16_t* ip = in + (size_t)bh * 2048 * 64;
  uint16_t* op = out + (size_t)bh * 64 * 2048;
  int tx = threadIdx.x, ty = threadIdx.y;
#pragma unroll
  for (int j = 0; j < 32; j += 8)
    tile[ty + j][tx] = ip[(size_t)(t0 + ty + j) * 64 + d0 + tx];
  __syncthreads();
#pragma unroll
  for (int j = 0; j < 32; j += 8)
    op[(size_t)(d0 + ty + j) * 2048 + t0 + tx] = tile[tx][ty + j];
}

// ---------------- GEMM (128x128 tile, BK=64, 4 waves) ----------------

__device__ __forceinline__ void stage16(const uint16_t* g, uint16_t* lds) {
  __builtin_amdgcn_global_load_lds((__attribute__((address_space(1))) void*)g,
                                   (__attribute__((address_space(3))) void*)lds, 16, 0, 0);
}

// C[M][N] = A[M][K] * Bt[N][K]^T + bias
// MODE 0: scatter bf16 into q/k/v [B,H,T,D]; MODE 1: plain f32 row-major out
template <int MODE>
__global__ __launch_bounds__(256) void gemm128(
    const uint16_t* __restrict__ A, const uint16_t* __restrict__ Bt,
    const float* __restrict__ bias, int K,
    uint16_t* __restrict__ q_out, uint16_t* __restrict__ k_out, uint16_t* __restrict__ v_out,
    float* __restrict__ f_out, int N) {
  __shared__ uint16_t lA[128 * 64];
  __shared__ uint16_t lB[128 * 64];
  const int tid = threadIdx.x;
  const int lane = tid & 63;
  const int w = tid >> 6, wm = w >> 1, wn = w & 1;
  const int r16 = lane & 15, hi = lane >> 4;
  const int bn = blockIdx.x, bm = blockIdx.y;

  f32x4 acc[4][4];
#pragma unroll
  for (int i = 0; i < 4; ++i)
#pragma unroll
    for (int j = 0; j < 4; ++j) acc[i][j] = (f32x4){0.f, 0.f, 0.f, 0.f};

  const int ksteps = K >> 6;
  for (int kt = 0; kt < ksteps; ++kt) {
#pragma unroll
    for (int it = 0; it < 4; ++it) {
      int ci = it * 256 + tid;       // 16B chunk index, 0..1023
      int row = ci >> 3;             // tile row 0..127
      int cch = (ci & 7) ^ (row & 7);// swizzled source column-chunk
      stage16(A + (size_t)(bm * 128 + row) * K + kt * 64 + cch * 8, &lA[ci * 8]);
      stage16(Bt + (size_t)(bn * 128 + row) * K + kt * 64 + cch * 8, &lB[ci * 8]);
    }
    __syncthreads();
#pragma unroll
    for (int kk = 0; kk < 2; ++kk) {
      short8 af[4], bfr[4];
      int swz = (kk * 64 + hi * 16) ^ ((r16 & 7) << 4);  // byte offset within 128B row
#pragma unroll
      for (int i = 0; i < 4; ++i) {
        int rowa = wm * 64 + i * 16 + r16;
        af[i] = *(const short8*)((const char*)lA + rowa * 128 + swz);
        int rowb = wn * 64 + i * 16 + r16;
        bfr[i] = *(const short8*)((const char*)lB + rowb * 128 + swz);
      }
#pragma unroll
      for (int i = 0; i < 4; ++i)
#pragma unroll
        for (int j = 0; j < 4; ++j)
          acc[i][j] = __builtin_amdgcn_mfma_f32_16x16x32_bf16(af[i], bfr[j], acc[i][j], 0, 0, 0);
    }
    __syncthreads();
  }

  // epilogue: D row = (lane>>4)*4 + r, col = lane&15  [verified m89/m91]
#pragma unroll
  for (int i = 0; i < 4; ++i) {
    int rbase = bm * 128 + wm * 64 + i * 16 + hi * 4;
#pragma unroll
    for (int j = 0; j < 4; ++j) {
      int cg = bn * 128 + wn * 64 + j * 16 + r16;
      float bv = bias[cg];
      if (MODE == 0) {
        int which = cg >> 10, hh = (cg >> 6) & 15, dd = cg & 63;
        uint16_t* dst = which == 0 ? q_out : (which == 1 ? k_out : v_out);
#pragma unroll
        for (int r = 0; r < 4; ++r) {
          int rg = rbase + r;
          int bb = rg >> 11, tt = rg & 2047;
          dst[((size_t)(bb * 16 + hh) * 2048 + tt) * 64 + dd] = f2bf(acc[i][j][r] + bv);
        }
      } else {
#pragma unroll
        for (int r = 0; r < 4; ++r) {
          int rg = rbase + r;
          f_out[(size_t)rg * N + cg] = acc[i][j][r] + bv;
        }
      }
    }
  }
}

// ---------------- causal flash attention ----------------
// Q,K: [BH][2048][64] bf16; Vt: [BH][64][2048] bf16; O: [B,T,C] bf16
// Block = 2 waves sharing a balanced strip-pair (s, 63-s), processed
// sequentially; per strip the KV tiles are split between the two waves
// (split-KV). Fixed-max softmax makes the merge a plain sum (o, l) via LDS.
// Every block does exactly ~33 tiles -> 8 blocks/CU, all resident, flat
// occupancy. bid decode pins each bh's K/V to one XCD's L2.
// launch_bounds (128,3): VGPR cap 170 (round 3's proven headroom); (128,4)
// capped at 128 and spilled ~430MB of scratch traffic (round 4 post-mortem).
__global__ __launch_bounds__(128, 3) void attn_fwd(
    const uint16_t* __restrict__ Qm, const uint16_t* __restrict__ Km,
    const uint16_t* __restrict__ Vt, uint16_t* __restrict__ O) {
  __shared__ uint16_t plds[2][16 * 72];  // per-wave P staging (rows padded to 72)
  __shared__ float mrg[34][64];          // wave1 partials: 32 o + 2 l per lane
  const int lane = threadIdx.x & 63;
  const int w = threadIdx.x >> 6;
  const int r16 = lane & 15, hi = lane >> 4;
  const int bid = blockIdx.x;
  const int pair = (bid >> 3) & 31;
  const int bh = (bid & 7) + ((bid >> 8) << 3);
  const int b = bh >> 4, h = bh & 15;
  const size_t base = (size_t)bh * 2048 * 64;

  const float SC = 0.18033688011112042f;   // 0.125 * log2(e)
  const float BIAS = -20.197730572445487f; // -14 * log2(e)

  short8 ones8;
#pragma unroll
  for (int i = 0; i < 8; ++i) ones8[i] = (short)0x3F80;  // bf16 1.0

#pragma unroll 1
  for (int halfp = 0; halfp < 2; ++halfp) {
    const int ss = halfp ? (63 - pair) : pair;
    const int q0 = ss * 32;
    const int nt = (ss >> 1) + 1;
    const int tsplit = (nt + 1) >> 1;
    const int t0 = w ? tsplit : 0;
    const int t1 = w ? nt : tsplit;

    short8 aq[2][2];
#pragma unroll
    for (int st = 0; st < 2; ++st)
#pragma unroll
      for (int c = 0; c < 2; ++c)
        aq[st][c] = *(const short8*)&Qm[base + (size_t)(q0 + st * 16 + r16) * 64 + c * 32 + hi * 8];

    f32x4 o[2][4];   // O^T fragments: col=q (r16), row=d (j*16+hi*4+r)
    f32x4 o4[2];     // l accumulator (every reg = l[q=r16])
#pragma unroll
    for (int st = 0; st < 2; ++st) {
#pragma unroll
      for (int j = 0; j < 4; ++j) o[st][j] = (f32x4){0.f, 0.f, 0.f, 0.f};
      o4[st] = (f32x4){0.f, 0.f, 0.f, 0.f};
    }

#pragma unroll 1
    for (int t = t0; t < t1; ++t) {
      const int kv0 = t << 6;
      const bool maskt = (t == nt - 1);
      short8 bk[4][2];
#pragma unroll
      for (int ct = 0; ct < 4; ++ct)
#pragma unroll
        for (int c = 0; c < 2; ++c)
          bk[ct][c] = *(const short8*)&Km[base + (size_t)(kv0 + ct * 16 + r16) * 64 + c * 32 + hi * 8];

#pragma unroll
      for (int st = 0; st < 2; ++st) {
        f32x4 sc[4];
#pragma unroll
        for (int ct = 0; ct < 4; ++ct) sc[ct] = (f32x4){0.f, 0.f, 0.f, 0.f};
#pragma unroll
        for (int ct = 0; ct < 4; ++ct)
#pragma unroll
          for (int c = 0; c < 2; ++c)
            sc[ct] = __builtin_amdgcn_mfma_f32_16x16x32_bf16(aq[st][c], bk[ct][c], sc[ct], 0, 0, 0);

        uint16_t* pl = &plds[w][0];
        const int rowq = q0 + st * 16 + hi * 4;
#pragma unroll
        for (int ct = 0; ct < 4; ++ct)
#pragma unroll
          for (int r = 0; r < 4; ++r) {
            float p = exp2f(fmaf(sc[ct][r], SC, BIAS));
            if (maskt && (kv0 + ct * 16 + r16) > (rowq + r)) p = 0.f;
            pl[(hi * 4 + r) * 72 + ct * 16 + r16] = f2bf_hw(p);
          }

        // order LDS writes before reads (single wave, DS pipe in-order)
        asm volatile("s_waitcnt lgkmcnt(0)" ::: "memory");
        __builtin_amdgcn_sched_barrier(0);

        short8 ap[2];
#pragma unroll
        for (int ks = 0; ks < 2; ++ks)
          ap[ks] = *(const short8*)&plds[w][r16 * 72 + ks * 32 + hi * 8];
#pragma unroll
        for (int ks = 0; ks < 2; ++ks)
          o4[st] = __builtin_amdgcn_mfma_f32_16x16x32_bf16(ones8, ap[ks], o4[st], 0, 0, 0);
#pragma unroll
        for (int ks = 0; ks < 2; ++ks) {
          short8 bv[4];
#pragma unroll
          for (int j = 0; j < 4; ++j)
            bv[j] = *(const short8*)&Vt[base + (size_t)(j * 16 + r16) * 2048 + kv0 + ks * 32 + hi * 8];
#pragma unroll
          for (int j = 0; j < 4; ++j)
            o[st][j] = __builtin_amdgcn_mfma_f32_16x16x32_bf16(bv[j], ap[ks], o[st][j], 0, 0, 0);
        }
      }
    }

    __syncthreads();
    if (w == 1) {
#pragma unroll
      for (int st = 0; st < 2; ++st) {
#pragma unroll
        for (int j = 0; j < 4; ++j)
#pragma unroll
          for (int r = 0; r < 4; ++r)
            mrg[st * 16 + j * 4 + r][lane] = o[st][j][r];
        mrg[32 + st][lane] = o4[st][0];
      }
    }
    __syncthreads();
    if (w == 0) {
#pragma unroll
      for (int st = 0; st < 2; ++st) {
        float lsum = o4[st][0] + mrg[32 + st][lane];
        float inv = 1.f / lsum;
        int qg = q0 + st * 16 + r16;
        size_t rowo = ((size_t)(b * 2048 + qg)) * 1024 + h * 64;
#pragma unroll
        for (int j = 0; j < 4; ++j) {
          float v0 = o[st][j][0] + mrg[st * 16 + j * 4 + 0][lane];
          float v1 = o[st][j][1] + mrg[st * 16 + j * 4 + 1][lane];
          float v2 = o[st][j][2] + mrg[st * 16 + j * 4 + 2][lane];
          float v3 = o[st][j][3] + mrg[st * 16 + j * 4 + 3][lane];
          ushort4_t v4 = { f2bf(v0 * inv), f2bf(v1 * inv), f2bf(v2 * inv), f2bf(v3 * inv) };
          *(ushort4_t*)&O[rowo + j * 16 + hi * 4] = v4;
        }
      }
    }
  }
}

// ---------------- launch ----------------

extern "C" void kernel_launch(void* const* d_in, const int* in_sizes, int n_in,
                              void* d_out, int out_size, void* d_ws, size_t ws_size,
                              hipStream_t stream) {
  const float* x = (const float*)d_in[0];
  const float* w_qkv = (const float*)d_in[1];
  const float* b_qkv = (const float*)d_in[2];
  const float* w_out = (const float*)d_in[3];
  const float* b_out = (const float*)d_in[4];
  float* out = (float*)d_out;

  const size_t BT = 8192, C = 1024, N3 = 3072, BHTD = 8388608;
  char* p = (char*)d_ws;
  uint16_t* xbf = (uint16_t*)p;   p += BT * C * 2;
  uint16_t* wqkvT = (uint16_t*)p; p += N3 * C * 2;
  uint16_t* woutT = (uint16_t*)p; p += C * C * 2;
  uint16_t* qb = (uint16_t*)p;    p += BHTD * 2;
  uint16_t* kb = (uint16_t*)p;    p += BHTD * 2;
  uint16_t* vb = (uint16_t*)p;    p += BHTD * 2;
  uint16_t* vtb = (uint16_t*)p;   p += BHTD * 2;
  uint16_t* ob = (uint16_t*)p;    p += BHTD * 2;

  cvt_f32_bf16<<<2048, 256, 0, stream>>>(x, xbf, (int)(BT * C / 4));
  transpose_cvt<<<dim3(96, 32), dim3(32, 8), 0, stream>>>(w_qkv, wqkvT, 1024, 3072);
  transpose_cvt<<<dim3(32, 32), dim3(32, 8), 0, stream>>>(w_out, woutT, 1024, 1024);
  gemm128<0><<<dim3(24, 64), 256, 0, stream>>>(xbf, wqkvT, b_qkv, 1024, qb, kb, vb, nullptr, 3072);
  transpose_v<<<dim3(64, 2, 64), dim3(32, 8), 0, stream>>>(vb, vtb);
  attn_fwd<<<2048, 128, 0, stream>>>(qb, kb, vtb, ob);
  gemm128<1><<<dim3(8, 64), 256, 0, stream>>>(ob, woutT, b_out, 1024, nullptr, nullptr, nullptr, out, 1024);
}

// Round 6
// 191.490 us; speedup vs baseline: 1.8298x; 1.6984x over previous
//
#include <hip/hip_runtime.h>
#include <hip/hip_bf16.h>
#include <cstdint>
#include <cstddef>

typedef __attribute__((ext_vector_type(8))) short short8;
typedef __attribute__((ext_vector_type(4))) float f32x4;
typedef __attribute__((ext_vector_type(4))) uint16_t ushort4_t;

__device__ __forceinline__ uint16_t f2bf(float f) {
  union { float f; uint32_t u; } v; v.f = f;
  uint32_t r = v.u + 0x7FFFu + ((v.u >> 16) & 1u);
  return (uint16_t)(r >> 16);
}

__device__ __forceinline__ uint16_t f2bf_hw(float f) {
  union { __hip_bfloat16 h; uint16_t u; } cv;
  cv.h = __float2bfloat16(f);
  return cv.u;
}

// ---------------- conversion kernels ----------------

__global__ __launch_bounds__(256) void cvt_f32_bf16(const float* __restrict__ in,
                                                    uint16_t* __restrict__ out, int n4) {
  int i = blockIdx.x * 256 + threadIdx.x;
  int stride = gridDim.x * 256;
  for (; i < n4; i += stride) {
    float4 v = ((const float4*)in)[i];
    ushort4_t o = { f2bf(v.x), f2bf(v.y), f2bf(v.z), f2bf(v.w) };
    ((ushort4_t*)out)[i] = o;
  }
}

// out[C][R] (bf16) = transpose of in[R][C] (f32)
__global__ __launch_bounds__(256) void transpose_cvt(const float* __restrict__ in,
                                                     uint16_t* __restrict__ out, int R, int C) {
  __shared__ float tile[32][33];
  int c0 = blockIdx.x * 32, r0 = blockIdx.y * 32;
  int tx = threadIdx.x, ty = threadIdx.y;
#pragma unroll
  for (int j = 0; j < 32; j += 8)
    tile[ty + j][tx] = in[(size_t)(r0 + ty + j) * C + c0 + tx];
  __syncthreads();
#pragma unroll
  for (int j = 0; j < 32; j += 8)
    out[(size_t)(c0 + ty + j) * R + r0 + tx] = f2bf(tile[tx][ty + j]);
}

// v [BH][2048][64] bf16 -> vT [BH][64][2048] bf16
__global__ __launch_bounds__(256) void transpose_v(const uint16_t* __restrict__ in,
                                                   uint16_t* __restrict__ out) {
  __shared__ uint16_t tile[32][33];
  int bh = blockIdx.z;
  int t0 = blockIdx.x * 32, d0 = blockIdx.y * 32;
  const uint16_t* ip = in + (size_t)bh * 2048 * 64;
  uint16_t* op = out + (size_t)bh * 64 * 2048;
  int tx = threadIdx.x, ty = threadIdx.y;
#pragma unroll
  for (int j = 0; j < 32; j += 8)
    tile[ty + j][tx] = ip[(size_t)(t0 + ty + j) * 64 + d0 + tx];
  __syncthreads();
#pragma unroll
  for (int j = 0; j < 32; j += 8)
    op[(size_t)(d0 + ty + j) * 2048 + t0 + tx] = tile[tx][ty + j];
}

// ---------------- GEMM (128x128 tile, BK=64, 4 waves) ----------------

__device__ __forceinline__ void stage16(const uint16_t* g, uint16_t* lds) {
  __builtin_amdgcn_global_load_lds((__attribute__((address_space(1))) void*)g,
                                   (__attribute__((address_space(3))) void*)lds, 16, 0, 0);
}

// C[M][N] = A[M][K] * Bt[N][K]^T + bias
// MODE 0: scatter bf16 into q/k/v [B,H,T,D]; MODE 1: plain f32 row-major out
template <int MODE>
__global__ __launch_bounds__(256) void gemm128(
    const uint16_t* __restrict__ A, const uint16_t* __restrict__ Bt,
    const float* __restrict__ bias, int K,
    uint16_t* __restrict__ q_out, uint16_t* __restrict__ k_out, uint16_t* __restrict__ v_out,
    float* __restrict__ f_out, int N) {
  __shared__ uint16_t lA[128 * 64];
  __shared__ uint16_t lB[128 * 64];
  const int tid = threadIdx.x;
  const int lane = tid & 63;
  const int w = tid >> 6, wm = w >> 1, wn = w & 1;
  const int r16 = lane & 15, hi = lane >> 4;
  const int bn = blockIdx.x, bm = blockIdx.y;

  f32x4 acc[4][4];
#pragma unroll
  for (int i = 0; i < 4; ++i)
#pragma unroll
    for (int j = 0; j < 4; ++j) acc[i][j] = (f32x4){0.f, 0.f, 0.f, 0.f};

  const int ksteps = K >> 6;
  for (int kt = 0; kt < ksteps; ++kt) {
#pragma unroll
    for (int it = 0; it < 4; ++it) {
      int ci = it * 256 + tid;       // 16B chunk index, 0..1023
      int row = ci >> 3;             // tile row 0..127
      int cch = (ci & 7) ^ (row & 7);// swizzled source column-chunk
      stage16(A + (size_t)(bm * 128 + row) * K + kt * 64 + cch * 8, &lA[ci * 8]);
      stage16(Bt + (size_t)(bn * 128 + row) * K + kt * 64 + cch * 8, &lB[ci * 8]);
    }
    __syncthreads();
#pragma unroll
    for (int kk = 0; kk < 2; ++kk) {
      short8 af[4], bfr[4];
      int swz = (kk * 64 + hi * 16) ^ ((r16 & 7) << 4);  // byte offset within 128B row
#pragma unroll
      for (int i = 0; i < 4; ++i) {
        int rowa = wm * 64 + i * 16 + r16;
        af[i] = *(const short8*)((const char*)lA + rowa * 128 + swz);
        int rowb = wn * 64 + i * 16 + r16;
        bfr[i] = *(const short8*)((const char*)lB + rowb * 128 + swz);
      }
#pragma unroll
      for (int i = 0; i < 4; ++i)
#pragma unroll
        for (int j = 0; j < 4; ++j)
          acc[i][j] = __builtin_amdgcn_mfma_f32_16x16x32_bf16(af[i], bfr[j], acc[i][j], 0, 0, 0);
    }
    __syncthreads();
  }

  // epilogue: D row = (lane>>4)*4 + r, col = lane&15  [verified m89/m91]
#pragma unroll
  for (int i = 0; i < 4; ++i) {
    int rbase = bm * 128 + wm * 64 + i * 16 + hi * 4;
#pragma unroll
    for (int j = 0; j < 4; ++j) {
      int cg = bn * 128 + wn * 64 + j * 16 + r16;
      float bv = bias[cg];
      if (MODE == 0) {
        int which = cg >> 10, hh = (cg >> 6) & 15, dd = cg & 63;
        uint16_t* dst = which == 0 ? q_out : (which == 1 ? k_out : v_out);
#pragma unroll
        for (int r = 0; r < 4; ++r) {
          int rg = rbase + r;
          int bb = rg >> 11, tt = rg & 2047;
          dst[((size_t)(bb * 16 + hh) * 2048 + tt) * 64 + dd] = f2bf(acc[i][j][r] + bv);
        }
      } else {
#pragma unroll
        for (int r = 0; r < 4; ++r) {
          int rg = rbase + r;
          f_out[(size_t)rg * N + cg] = acc[i][j][r] + bv;
        }
      }
    }
  }
}

// ---------------- causal flash attention ----------------
// Q,K: [BH][2048][64] bf16; Vt: [BH][64][2048] bf16; O: [B,T,C] bf16
// Block = 4 waves, 128 q-rows (wave w owns rows qb*128+w*32..+31).
// K and Vt KV-64 tiles staged in LDS (double-buffered, global_load_lds w16,
// XOR-swizzled source + same-XOR read, rule #21), shared by all 4 waves.
// Prefetch 1 tile ahead; counted vmcnt(4) + raw s_barrier (never drain
// mid-loop). Fixed-max softmax (exact math); l via ones-MFMA; O^T epilogue.
// Grid: 1024 blocks, longest-first (qb descending), bh pinned per XCD.
__global__ __launch_bounds__(256, 3) void attn_fwd(
    const uint16_t* __restrict__ Qm, const uint16_t* __restrict__ Km,
    const uint16_t* __restrict__ Vt, uint16_t* __restrict__ O) {
  __shared__ uint16_t kbuf[2][64 * 64];
  __shared__ uint16_t vbuf[2][64 * 64];
  __shared__ uint16_t plds[4][32 * 72];
  const int tid = threadIdx.x;
  const int lane = tid & 63, w = tid >> 6;
  const int r16 = lane & 15, hi = lane >> 4;
  const int bid = blockIdx.x;
  const int bh = (bid & 7) + 8 * ((bid >> 3) & 7);  // XCD-pinned head
  const int qb = 15 - (bid >> 6);                   // longest strips first
  const int b = bh >> 4, h = bh & 15;
  const size_t base = (size_t)bh * 2048 * 64;
  const int qlo = qb * 128 + w * 32;                // wave's strip start
  const int NT = 2 * qb + 2;

  const float SC = 0.18033688011112042f;   // 0.125 * log2(e)
  const float BIAS = -20.197730572445487f; // -14 * log2(e)

  short8 ones8;
#pragma unroll
  for (int i = 0; i < 8; ++i) ones8[i] = (short)0x3F80;  // bf16 1.0

  // Q fragments for the whole kernel
  short8 aq[2][2];
#pragma unroll
  for (int st = 0; st < 2; ++st)
#pragma unroll
    for (int c = 0; c < 2; ++c)
      aq[st][c] = *(const short8*)&Qm[base + (size_t)(qlo + st * 16 + r16) * 64 + c * 32 + hi * 8];

  f32x4 o[2][4];   // O^T fragments: col=q (r16), row=d (j*16+hi*4+r)
  f32x4 o4[2];     // l accumulator (every reg = l[q=r16])
#pragma unroll
  for (int st = 0; st < 2; ++st) {
#pragma unroll
    for (int j = 0; j < 4; ++j) o[st][j] = (f32x4){0.f, 0.f, 0.f, 0.f};
    o4[st] = (f32x4){0.f, 0.f, 0.f, 0.f};
  }

  // stage one KV-64 tile (K 8KB + Vt 8KB), 4 chunks per thread
  auto stage_tile = [&](int pb, int kv0) {
    {
      int c = tid;            int row = c >> 3, cch = (c & 7) ^ (row & 7);
      stage16(Km + base + (size_t)(kv0 + row) * 64 + cch * 8, &kbuf[pb][c * 8]);
    }
    {
      int c = tid + 256;      int row = c >> 3, cch = (c & 7) ^ (row & 7);
      stage16(Km + base + (size_t)(kv0 + row) * 64 + cch * 8, &kbuf[pb][c * 8]);
    }
    {
      int c = tid;            int row = c >> 3, cch = (c & 7) ^ (row & 7);
      stage16(Vt + base + (size_t)row * 2048 + kv0 + cch * 8, &vbuf[pb][c * 8]);
    }
    {
      int c = tid + 256;      int row = c >> 3, cch = (c & 7) ^ (row & 7);
      stage16(Vt + base + (size_t)row * 2048 + kv0 + cch * 8, &vbuf[pb][c * 8]);
    }
  };

  int pb = 0;
  stage_tile(0, 0);
#pragma unroll 1
  for (int t = 0; t < NT; ++t) {
    const int kv0 = t << 6;
    if (t + 1 < NT) {
      stage_tile(pb ^ 1, (t + 1) << 6);
      asm volatile("s_waitcnt vmcnt(4)" ::: "memory");  // this tile's 4 done
    } else {
      asm volatile("s_waitcnt vmcnt(0)" ::: "memory");
    }
    __builtin_amdgcn_s_barrier();
    __builtin_amdgcn_sched_barrier(0);

    if (kv0 <= qlo + 31) {  // strip intersects this KV tile
      const bool maskt = (kv0 + 64 > qlo);
      // K fragments from LDS (swizzled read)
      short8 bk[4][2];
#pragma unroll
      for (int ct = 0; ct < 4; ++ct)
#pragma unroll
        for (int c = 0; c < 2; ++c) {
          int row = ct * 16 + r16;
          int ch = (c * 4 + hi) ^ (row & 7);
          bk[ct][c] = *(const short8*)((const char*)&kbuf[pb][0] + row * 128 + ch * 16);
        }

#pragma unroll
      for (int st = 0; st < 2; ++st) {
        f32x4 sc[4];
#pragma unroll
        for (int ct = 0; ct < 4; ++ct) sc[ct] = (f32x4){0.f, 0.f, 0.f, 0.f};
#pragma unroll
        for (int ct = 0; ct < 4; ++ct)
#pragma unroll
          for (int c = 0; c < 2; ++c)
            sc[ct] = __builtin_amdgcn_mfma_f32_16x16x32_bf16(aq[st][c], bk[ct][c], sc[ct], 0, 0, 0);

        uint16_t* pl = &plds[w][st * 16 * 72];
        const int rowq = qlo + st * 16 + hi * 4;
#pragma unroll
        for (int ct = 0; ct < 4; ++ct)
#pragma unroll
          for (int r = 0; r < 4; ++r) {
            float p = exp2f(fmaf(sc[ct][r], SC, BIAS));
            if (maskt && (kv0 + ct * 16 + r16) > (rowq + r)) p = 0.f;
            pl[(hi * 4 + r) * 72 + ct * 16 + r16] = f2bf_hw(p);
          }
      }
      // order P writes before P reads (wave-local, DS pipe)
      asm volatile("s_waitcnt lgkmcnt(0)" ::: "memory");
      __builtin_amdgcn_sched_barrier(0);

      short8 ap[2][2];
#pragma unroll
      for (int st = 0; st < 2; ++st)
#pragma unroll
        for (int ks = 0; ks < 2; ++ks)
          ap[st][ks] = *(const short8*)&plds[w][(st * 16 + r16) * 72 + ks * 32 + hi * 8];
      short8 bv[4][2];
#pragma unroll
      for (int j = 0; j < 4; ++j)
#pragma unroll
        for (int ks = 0; ks < 2; ++ks) {
          int row = j * 16 + r16;
          int ch = (ks * 4 + hi) ^ (row & 7);
          bv[j][ks] = *(const short8*)((const char*)&vbuf[pb][0] + row * 128 + ch * 16);
        }
#pragma unroll
      for (int st = 0; st < 2; ++st) {
#pragma unroll
        for (int ks = 0; ks < 2; ++ks)
          o4[st] = __builtin_amdgcn_mfma_f32_16x16x32_bf16(ones8, ap[st][ks], o4[st], 0, 0, 0);
#pragma unroll
        for (int j = 0; j < 4; ++j)
#pragma unroll
          for (int ks = 0; ks < 2; ++ks)
            o[st][j] = __builtin_amdgcn_mfma_f32_16x16x32_bf16(bv[j][ks], ap[st][ks], o[st][j], 0, 0, 0);
      }
    }

    __builtin_amdgcn_s_barrier();   // all reads of pb done before re-staging
    __builtin_amdgcn_sched_barrier(0);
    pb ^= 1;
  }

  // epilogue: O^T layout -> O[b][q][h*64 + d], 8B vector stores
#pragma unroll
  for (int st = 0; st < 2; ++st) {
    float inv = 1.f / o4[st][0];
    int qg = qlo + st * 16 + r16;
    size_t rowo = ((size_t)(b * 2048 + qg)) * 1024 + h * 64;
#pragma unroll
    for (int j = 0; j < 4; ++j) {
      ushort4_t v4 = { f2bf(o[st][j][0] * inv), f2bf(o[st][j][1] * inv),
                       f2bf(o[st][j][2] * inv), f2bf(o[st][j][3] * inv) };
      *(ushort4_t*)&O[rowo + j * 16 + hi * 4] = v4;
    }
  }
}

// ---------------- launch ----------------

extern "C" void kernel_launch(void* const* d_in, const int* in_sizes, int n_in,
                              void* d_out, int out_size, void* d_ws, size_t ws_size,
                              hipStream_t stream) {
  const float* x = (const float*)d_in[0];
  const float* w_qkv = (const float*)d_in[1];
  const float* b_qkv = (const float*)d_in[2];
  const float* w_out = (const float*)d_in[3];
  const float* b_out = (const float*)d_in[4];
  float* out = (float*)d_out;

  const size_t BT = 8192, C = 1024, N3 = 3072, BHTD = 8388608;
  char* p = (char*)d_ws;
  uint16_t* xbf = (uint16_t*)p;   p += BT * C * 2;
  uint16_t* wqkvT = (uint16_t*)p; p += N3 * C * 2;
  uint16_t* woutT = (uint16_t*)p; p += C * C * 2;
  uint16_t* qb = (uint16_t*)p;    p += BHTD * 2;
  uint16_t* kb = (uint16_t*)p;    p += BHTD * 2;
  uint16_t* vb = (uint16_t*)p;    p += BHTD * 2;
  uint16_t* vtb = (uint16_t*)p;   p += BHTD * 2;
  uint16_t* ob = (uint16_t*)p;    p += BHTD * 2;

  cvt_f32_bf16<<<2048, 256, 0, stream>>>(x, xbf, (int)(BT * C / 4));
  transpose_cvt<<<dim3(96, 32), dim3(32, 8), 0, stream>>>(w_qkv, wqkvT, 1024, 3072);
  transpose_cvt<<<dim3(32, 32), dim3(32, 8), 0, stream>>>(w_out, woutT, 1024, 1024);
  gemm128<0><<<dim3(24, 64), 256, 0, stream>>>(xbf, wqkvT, b_qkv, 1024, qb, kb, vb, nullptr, 3072);
  transpose_v<<<dim3(64, 2, 64), dim3(32, 8), 0, stream>>>(vb, vtb);
  attn_fwd<<<1024, 256, 0, stream>>>(qb, kb, vtb, ob);
  gemm128<1><<<dim3(8, 64), 256, 0, stream>>>(ob, woutT, b_out, 1024, nullptr, nullptr, nullptr, out, 1024);
}

// Round 7
// 187.419 us; speedup vs baseline: 1.8696x; 1.0217x over previous
//
#include <hip/hip_runtime.h>
#include <hip/hip_bf16.h>
#include <cstdint>
#include <cstddef>

typedef __attribute__((ext_vector_type(8))) short short8;
typedef __attribute__((ext_vector_type(4))) float f32x4;
typedef __attribute__((ext_vector_type(4))) uint16_t ushort4_t;

__device__ __forceinline__ uint16_t f2bf(float f) {
  union { float f; uint32_t u; } v; v.f = f;
  uint32_t r = v.u + 0x7FFFu + ((v.u >> 16) & 1u);
  return (uint16_t)(r >> 16);
}

__device__ __forceinline__ uint16_t f2bf_hw(float f) {
  union { __hip_bfloat16 h; uint16_t u; } cv;
  cv.h = __float2bfloat16(f);
  return cv.u;
}

// ---------------- conversion kernels ----------------

__global__ __launch_bounds__(256) void cvt_f32_bf16(const float* __restrict__ in,
                                                    uint16_t* __restrict__ out, int n4) {
  int i = blockIdx.x * 256 + threadIdx.x;
  int stride = gridDim.x * 256;
  for (; i < n4; i += stride) {
    float4 v = ((const float4*)in)[i];
    ushort4_t o = { f2bf(v.x), f2bf(v.y), f2bf(v.z), f2bf(v.w) };
    ((ushort4_t*)out)[i] = o;
  }
}

// out[C][R] (bf16) = transpose of in[R][C] (f32)
__global__ __launch_bounds__(256) void transpose_cvt(const float* __restrict__ in,
                                                     uint16_t* __restrict__ out, int R, int C) {
  __shared__ float tile[32][33];
  int c0 = blockIdx.x * 32, r0 = blockIdx.y * 32;
  int tx = threadIdx.x, ty = threadIdx.y;
#pragma unroll
  for (int j = 0; j < 32; j += 8)
    tile[ty + j][tx] = in[(size_t)(r0 + ty + j) * C + c0 + tx];
  __syncthreads();
#pragma unroll
  for (int j = 0; j < 32; j += 8)
    out[(size_t)(c0 + ty + j) * R + r0 + tx] = f2bf(tile[tx][ty + j]);
}

// v [BH][2048][64] bf16 -> vT [BH][64][2048] bf16
__global__ __launch_bounds__(256) void transpose_v(const uint16_t* __restrict__ in,
                                                   uint16_t* __restrict__ out) {
  __shared__ uint16_t tile[32][33];
  int bh = blockIdx.z;
  int t0 = blockIdx.x * 32, d0 = blockIdx.y * 32;
  const uint16_t* ip = in + (size_t)bh * 2048 * 64;
  uint16_t* op = out + (size_t)bh * 64 * 2048;
  int tx = threadIdx.x, ty = threadIdx.y;
#pragma unroll
  for (int j = 0; j < 32; j += 8)
    tile[ty + j][tx] = ip[(size_t)(t0 + ty + j) * 64 + d0 + tx];
  __syncthreads();
#pragma unroll
  for (int j = 0; j < 32; j += 8)
    op[(size_t)(d0 + ty + j) * 2048 + t0 + tx] = tile[tx][ty + j];
}

// ---------------- GEMM (128x128 tile, BK=64, 4 waves) ----------------

__device__ __forceinline__ void stage16(const uint16_t* g, uint16_t* lds) {
  __builtin_amdgcn_global_load_lds((__attribute__((address_space(1))) void*)g,
                                   (__attribute__((address_space(3))) void*)lds, 16, 0, 0);
}

// C[M][N] = A[M][K] * Bt[N][K]^T + bias
// MODE 0: scatter bf16 into q/k/v [B,H,T,D]; MODE 1: plain f32 row-major out
template <int MODE>
__global__ __launch_bounds__(256) void gemm128(
    const uint16_t* __restrict__ A, const uint16_t* __restrict__ Bt,
    const float* __restrict__ bias, int K,
    uint16_t* __restrict__ q_out, uint16_t* __restrict__ k_out, uint16_t* __restrict__ v_out,
    float* __restrict__ f_out, int N) {
  __shared__ uint16_t lA[128 * 64];
  __shared__ uint16_t lB[128 * 64];
  const int tid = threadIdx.x;
  const int lane = tid & 63;
  const int w = tid >> 6, wm = w >> 1, wn = w & 1;
  const int r16 = lane & 15, hi = lane >> 4;
  const int bn = blockIdx.x, bm = blockIdx.y;

  f32x4 acc[4][4];
#pragma unroll
  for (int i = 0; i < 4; ++i)
#pragma unroll
    for (int j = 0; j < 4; ++j) acc[i][j] = (f32x4){0.f, 0.f, 0.f, 0.f};

  const int ksteps = K >> 6;
  for (int kt = 0; kt < ksteps; ++kt) {
#pragma unroll
    for (int it = 0; it < 4; ++it) {
      int ci = it * 256 + tid;       // 16B chunk index, 0..1023
      int row = ci >> 3;             // tile row 0..127
      int cch = (ci & 7) ^ (row & 7);// swizzled source column-chunk
      stage16(A + (size_t)(bm * 128 + row) * K + kt * 64 + cch * 8, &lA[ci * 8]);
      stage16(Bt + (size_t)(bn * 128 + row) * K + kt * 64 + cch * 8, &lB[ci * 8]);
    }
    __syncthreads();
#pragma unroll
    for (int kk = 0; kk < 2; ++kk) {
      short8 af[4], bfr[4];
      int swz = (kk * 64 + hi * 16) ^ ((r16 & 7) << 4);  // byte offset within 128B row
#pragma unroll
      for (int i = 0; i < 4; ++i) {
        int rowa = wm * 64 + i * 16 + r16;
        af[i] = *(const short8*)((const char*)lA + rowa * 128 + swz);
        int rowb = wn * 64 + i * 16 + r16;
        bfr[i] = *(const short8*)((const char*)lB + rowb * 128 + swz);
      }
#pragma unroll
      for (int i = 0; i < 4; ++i)
#pragma unroll
        for (int j = 0; j < 4; ++j)
          acc[i][j] = __builtin_amdgcn_mfma_f32_16x16x32_bf16(af[i], bfr[j], acc[i][j], 0, 0, 0);
    }
    __syncthreads();
  }

  // epilogue: D row = (lane>>4)*4 + r, col = lane&15  [verified m89/m91]
#pragma unroll
  for (int i = 0; i < 4; ++i) {
    int rbase = bm * 128 + wm * 64 + i * 16 + hi * 4;
#pragma unroll
    for (int j = 0; j < 4; ++j) {
      int cg = bn * 128 + wn * 64 + j * 16 + r16;
      float bv = bias[cg];
      if (MODE == 0) {
        int which = cg >> 10, hh = (cg >> 6) & 15, dd = cg & 63;
        uint16_t* dst = which == 0 ? q_out : (which == 1 ? k_out : v_out);
#pragma unroll
        for (int r = 0; r < 4; ++r) {
          int rg = rbase + r;
          int bb = rg >> 11, tt = rg & 2047;
          dst[((size_t)(bb * 16 + hh) * 2048 + tt) * 64 + dd] = f2bf(acc[i][j][r] + bv);
        }
      } else {
#pragma unroll
        for (int r = 0; r < 4; ++r) {
          int rg = rbase + r;
          f_out[(size_t)rg * N + cg] = acc[i][j][r] + bv;
        }
      }
    }
  }
}

// ---------------- causal flash attention ----------------
// Q,K: [BH][2048][64] bf16; Vt: [BH][64][2048] bf16; O: [B,T,C] bf16
// Block = 4 waves, 128 q-rows. K/Vt KV-64 tiles staged in LDS (dbuf,
// global_load_lds w16, XOR swizzle both sides), counted vmcnt + raw barriers.
// SWAPPED QK^T: sc = mfma(K-frag, Q-frag) -> S^T (col=q=r16, row=k).
// Each lane then holds runs of 4 consecutive k -> P packs to ushort4 and
// stores with 8 ds_write_b64 per tile-wave (was 32 ds_write_b16 + 32 cvt).
// Fixed-max softmax (exact); l via ones-MFMA; O^T epilogue; setprio on MFMA.
__global__ __launch_bounds__(256, 3) void attn_fwd(
    const uint16_t* __restrict__ Qm, const uint16_t* __restrict__ Km,
    const uint16_t* __restrict__ Vt, uint16_t* __restrict__ O) {
  __shared__ uint16_t kbuf[2][64 * 64];
  __shared__ uint16_t vbuf[2][64 * 64];
  __shared__ uint16_t plds[4][32 * 72];
  const int tid = threadIdx.x;
  const int lane = tid & 63, w = tid >> 6;
  const int r16 = lane & 15, hi = lane >> 4;
  const int bid = blockIdx.x;
  const int bh = (bid & 7) + 8 * ((bid >> 3) & 7);  // XCD-pinned head
  const int qb = 15 - (bid >> 6);                   // longest strips first
  const int b = bh >> 4, h = bh & 15;
  const size_t base = (size_t)bh * 2048 * 64;
  const int qlo = qb * 128 + w * 32;                // wave's strip start
  const int NT = 2 * qb + 2;

  const float SC = 0.18033688011112042f;   // 0.125 * log2(e)
  const float BIAS = -20.197730572445487f; // -14 * log2(e)

  short8 ones8;
#pragma unroll
  for (int i = 0; i < 8; ++i) ones8[i] = (short)0x3F80;  // bf16 1.0

  // Q fragments for the whole kernel
  short8 aq[2][2];
#pragma unroll
  for (int st = 0; st < 2; ++st)
#pragma unroll
    for (int c = 0; c < 2; ++c)
      aq[st][c] = *(const short8*)&Qm[base + (size_t)(qlo + st * 16 + r16) * 64 + c * 32 + hi * 8];

  f32x4 o[2][4];   // O^T fragments: col=q (r16), row=d (j*16+hi*4+r)
  f32x4 o4[2];     // l accumulator (every reg = l[q=r16])
#pragma unroll
  for (int st = 0; st < 2; ++st) {
#pragma unroll
    for (int j = 0; j < 4; ++j) o[st][j] = (f32x4){0.f, 0.f, 0.f, 0.f};
    o4[st] = (f32x4){0.f, 0.f, 0.f, 0.f};
  }

  // stage one KV-64 tile (K 8KB + Vt 8KB), 4 chunks per thread
  auto stage_tile = [&](int pb, int kv0) {
    {
      int c = tid;            int row = c >> 3, cch = (c & 7) ^ (row & 7);
      stage16(Km + base + (size_t)(kv0 + row) * 64 + cch * 8, &kbuf[pb][c * 8]);
    }
    {
      int c = tid + 256;      int row = c >> 3, cch = (c & 7) ^ (row & 7);
      stage16(Km + base + (size_t)(kv0 + row) * 64 + cch * 8, &kbuf[pb][c * 8]);
    }
    {
      int c = tid;            int row = c >> 3, cch = (c & 7) ^ (row & 7);
      stage16(Vt + base + (size_t)row * 2048 + kv0 + cch * 8, &vbuf[pb][c * 8]);
    }
    {
      int c = tid + 256;      int row = c >> 3, cch = (c & 7) ^ (row & 7);
      stage16(Vt + base + (size_t)row * 2048 + kv0 + cch * 8, &vbuf[pb][c * 8]);
    }
  };

  int pb = 0;
  stage_tile(0, 0);
#pragma unroll 1
  for (int t = 0; t < NT; ++t) {
    const int kv0 = t << 6;
    if (t + 1 < NT) {
      stage_tile(pb ^ 1, (t + 1) << 6);
      asm volatile("s_waitcnt vmcnt(4)" ::: "memory");  // this tile's 4 done
    } else {
      asm volatile("s_waitcnt vmcnt(0)" ::: "memory");
    }
    __builtin_amdgcn_s_barrier();
    __builtin_amdgcn_sched_barrier(0);

    if (kv0 <= qlo + 31) {  // strip intersects this KV tile
      const bool maskt = (kv0 + 64 > qlo);
      // K fragments from LDS (swizzled read)
      short8 bk[4][2];
#pragma unroll
      for (int ct = 0; ct < 4; ++ct)
#pragma unroll
        for (int c = 0; c < 2; ++c) {
          int row = ct * 16 + r16;
          int ch = (c * 4 + hi) ^ (row & 7);
          bk[ct][c] = *(const short8*)((const char*)&kbuf[pb][0] + row * 128 + ch * 16);
        }

#pragma unroll
      for (int st = 0; st < 2; ++st) {
        // swapped QK^T: S^T col=q=r16, row=k_local=ct*16+hi*4+r
        f32x4 sc[4];
#pragma unroll
        for (int ct = 0; ct < 4; ++ct) sc[ct] = (f32x4){0.f, 0.f, 0.f, 0.f};
        __builtin_amdgcn_s_setprio(1);
#pragma unroll
        for (int ct = 0; ct < 4; ++ct)
#pragma unroll
          for (int c = 0; c < 2; ++c)
            sc[ct] = __builtin_amdgcn_mfma_f32_16x16x32_bf16(bk[ct][c], aq[st][c], sc[ct], 0, 0, 0);
        __builtin_amdgcn_s_setprio(0);

        uint16_t* pl = &plds[w][st * 16 * 72];
        const int qg = qlo + st * 16 + r16;   // this lane's q (column)
#pragma unroll
        for (int ct = 0; ct < 4; ++ct) {
          const int kb_ = kv0 + ct * 16 + hi * 4;
          float p0 = exp2f(fmaf(sc[ct][0], SC, BIAS));
          float p1 = exp2f(fmaf(sc[ct][1], SC, BIAS));
          float p2 = exp2f(fmaf(sc[ct][2], SC, BIAS));
          float p3 = exp2f(fmaf(sc[ct][3], SC, BIAS));
          if (maskt) {
            if (kb_ + 0 > qg) p0 = 0.f;
            if (kb_ + 1 > qg) p1 = 0.f;
            if (kb_ + 2 > qg) p2 = 0.f;
            if (kb_ + 3 > qg) p3 = 0.f;
          }
          ushort4_t pk4 = { f2bf_hw(p0), f2bf_hw(p1), f2bf_hw(p2), f2bf_hw(p3) };
          *(ushort4_t*)&pl[r16 * 72 + ct * 16 + hi * 4] = pk4;  // ds_write_b64
        }
      }
      // order P writes before P reads (wave-local, DS pipe)
      asm volatile("s_waitcnt lgkmcnt(0)" ::: "memory");
      __builtin_amdgcn_sched_barrier(0);

      short8 ap[2][2];
#pragma unroll
      for (int st = 0; st < 2; ++st)
#pragma unroll
        for (int ks = 0; ks < 2; ++ks)
          ap[st][ks] = *(const short8*)&plds[w][(st * 16 + r16) * 72 + ks * 32 + hi * 8];
      short8 bv[4][2];
#pragma unroll
      for (int j = 0; j < 4; ++j)
#pragma unroll
        for (int ks = 0; ks < 2; ++ks) {
          int row = j * 16 + r16;
          int ch = (ks * 4 + hi) ^ (row & 7);
          bv[j][ks] = *(const short8*)((const char*)&vbuf[pb][0] + row * 128 + ch * 16);
        }
      __builtin_amdgcn_s_setprio(1);
#pragma unroll
      for (int st = 0; st < 2; ++st) {
#pragma unroll
        for (int ks = 0; ks < 2; ++ks)
          o4[st] = __builtin_amdgcn_mfma_f32_16x16x32_bf16(ones8, ap[st][ks], o4[st], 0, 0, 0);
#pragma unroll
        for (int j = 0; j < 4; ++j)
#pragma unroll
          for (int ks = 0; ks < 2; ++ks)
            o[st][j] = __builtin_amdgcn_mfma_f32_16x16x32_bf16(bv[j][ks], ap[st][ks], o[st][j], 0, 0, 0);
      }
      __builtin_amdgcn_s_setprio(0);
    }

    __builtin_amdgcn_s_barrier();   // all reads of pb done before re-staging
    __builtin_amdgcn_sched_barrier(0);
    pb ^= 1;
  }

  // epilogue: O^T layout -> O[b][q][h*64 + d], 8B vector stores
#pragma unroll
  for (int st = 0; st < 2; ++st) {
    float inv = 1.f / o4[st][0];
    int qg = qlo + st * 16 + r16;
    size_t rowo = ((size_t)(b * 2048 + qg)) * 1024 + h * 64;
#pragma unroll
    for (int j = 0; j < 4; ++j) {
      ushort4_t v4 = { f2bf(o[st][j][0] * inv), f2bf(o[st][j][1] * inv),
                       f2bf(o[st][j][2] * inv), f2bf(o[st][j][3] * inv) };
      *(ushort4_t*)&O[rowo + j * 16 + hi * 4] = v4;
    }
  }
}

// ---------------- launch ----------------

extern "C" void kernel_launch(void* const* d_in, const int* in_sizes, int n_in,
                              void* d_out, int out_size, void* d_ws, size_t ws_size,
                              hipStream_t stream) {
  const float* x = (const float*)d_in[0];
  const float* w_qkv = (const float*)d_in[1];
  const float* b_qkv = (const float*)d_in[2];
  const float* w_out = (const float*)d_in[3];
  const float* b_out = (const float*)d_in[4];
  float* out = (float*)d_out;

  const size_t BT = 8192, C = 1024, N3 = 3072, BHTD = 8388608;
  char* p = (char*)d_ws;
  uint16_t* xbf = (uint16_t*)p;   p += BT * C * 2;
  uint16_t* wqkvT = (uint16_t*)p; p += N3 * C * 2;
  uint16_t* woutT = (uint16_t*)p; p += C * C * 2;
  uint16_t* qb = (uint16_t*)p;    p += BHTD * 2;
  uint16_t* kb = (uint16_t*)p;    p += BHTD * 2;
  uint16_t* vb = (uint16_t*)p;    p += BHTD * 2;
  uint16_t* vtb = (uint16_t*)p;   p += BHTD * 2;
  uint16_t* ob = (uint16_t*)p;    p += BHTD * 2;

  cvt_f32_bf16<<<2048, 256, 0, stream>>>(x, xbf, (int)(BT * C / 4));
  transpose_cvt<<<dim3(96, 32), dim3(32, 8), 0, stream>>>(w_qkv, wqkvT, 1024, 3072);
  transpose_cvt<<<dim3(32, 32), dim3(32, 8), 0, stream>>>(w_out, woutT, 1024, 1024);
  gemm128<0><<<dim3(24, 64), 256, 0, stream>>>(xbf, wqkvT, b_qkv, 1024, qb, kb, vb, nullptr, 3072);
  transpose_v<<<dim3(64, 2, 64), dim3(32, 8), 0, stream>>>(vb, vtb);
  attn_fwd<<<1024, 256, 0, stream>>>(qb, kb, vtb, ob);
  gemm128<1><<<dim3(8, 64), 256, 0, stream>>>(ob, woutT, b_out, 1024, nullptr, nullptr, nullptr, out, 1024);
}